// Round 4
// baseline (308.286 us; speedup 1.0000x reference)
//
#include <hip/hip_runtime.h>
#include <hip/hip_bf16.h>

// Problem constants
#define B_ROWS 16384
#define K_DIM  1024
#define N_INT  1023
#define N_OUT  1000

using s8vec = __attribute__((ext_vector_type(8))) short;   // 8 bf16 (4 VGPRs) MFMA operand
using f32x4 = __attribute__((ext_vector_type(4))) float;   // MFMA accumulator

// Workspace layout (bytes). Total ~105 MB.
static const size_t OFF_XB   = 0;                        // bf16 [16384*1024]; DEAD after gemm<0> -> reused as Spart
static const size_t OFF_W1   = OFF_XB   + 33554432;      // bf16 [1024*1024] (row 1023 = 0)
static const size_t OFF_BIAS = OFF_W1   + 2097152;       // f32  [1024]
static const size_t OFF_PROB = OFF_BIAS + 4096;          // bf16 [16384*1024]; node j at col j+1
static const size_t OFF_PATH = OFF_PROB + 33554432;      // bf16 [16384*1024]
static const size_t OFF_W2   = OFF_PATH + 33554432;      // bf16 [1024*1024] (rows >=1000 = 0)
static const size_t OFF_SG   = OFF_W2   + 2097152;       // f32  [4096]: S1 at [node], S2 at [2048+node]

__device__ __forceinline__ float b2f(ushort u) {
  return __uint_as_float(((unsigned)u) << 16);
}
__device__ __forceinline__ float blo(unsigned u) { return __uint_as_float(u << 16); }
__device__ __forceinline__ float bhi(unsigned u) { return __uint_as_float(u & 0xffff0000u); }
__device__ __forceinline__ ushort f2b(float f) {
  unsigned u = __float_as_uint(f);
  u = u + 0x7FFFu + ((u >> 16) & 1u);   // RNE
  return (ushort)(u >> 16);
}

// async global->LDS, 16B per lane; LDS dest is wave-uniform base + lane*16
__device__ __forceinline__ void load_lds16(const ushort* g, ushort* l) {
  __builtin_amdgcn_global_load_lds((const __attribute__((address_space(1))) void*)g,
                                   (__attribute__((address_space(3))) void*)l,
                                   16, 0, 0);
}

// ---------------- fused converts (one launch) ----------------
__global__ __launch_bounds__(256) void cvt_all(const float4* __restrict__ X,
                                               ushort4* __restrict__ O,
                                               const float* __restrict__ Wi,
                                               const float* __restrict__ Wl,
                                               ushort* __restrict__ W1,
                                               ushort* __restrict__ W2,
                                               float* __restrict__ bias) {
  const int b = blockIdx.x;
  if (b < 16384) {
    const int i = b * 256 + threadIdx.x;
    const float4 v = X[i];
    ushort4 o;
    o.x = f2b(v.x); o.y = f2b(v.y); o.z = f2b(v.z); o.w = f2b(v.w);
    O[i] = o;
  } else {
    const int idx = (b - 16384) * 256 + threadIdx.x;   // [0, 2*2^20)
    if (idx < (1 << 20)) {
      const int n = idx >> 10, k = idx & 1023;
      const float v = (n < N_INT) ? Wi[n * 1025 + 1 + k] : 0.f;
      W1[idx] = f2b(v);
      if (k == 0) bias[n] = (n < N_INT) ? Wi[n * 1025] : 0.f;
    } else {
      const int j = idx - (1 << 20);
      const int n = j >> 10, k = j & 1023;
      const float v = (n < N_OUT) ? Wl[n * 1024 + k] : 0.f;
      W2[j] = f2b(v);
    }
  }
}

// ---------------- GEMM: C = A[M,K] * Bm[N,K]^T, 128x128 tile, 4 waves ----------------
// T3+T4 2-phase pipeline: LDS double-buffer; STAGE(next) issued at TOP of the
// iteration, then COUNTED s_waitcnt vmcnt(4) (waits only the current tile's 4
// global_load_lds; next tile's 4 stay in flight across both barriers) + raw
// s_barrier in one volatile asm (memory clobber pins ordering; avoids
// __syncthreads' vmcnt(0) drain which would kill the overlap).
// LDS chunk-swizzle (slot = q ^ ((row>>1)&3)) on GLOBAL source + ds_read addr.
// Grid (bm fast, bn=8): all 8 bn-blocks of an A strip share one XCD's L2.
template <int MODE>
__global__ __launch_bounds__(256, 4) void gemm_bt(const ushort* __restrict__ A,
                                                  const ushort* __restrict__ Bm,
                                                  const float* __restrict__ bias,
                                                  void* __restrict__ outp) {
  __shared__ ushort As[2][4096];   // [buf][128 rows][32 k] bf16, chunk-swizzled
  __shared__ ushort Bs[2][4096];
  const int tid = threadIdx.x;
  const int bm = blockIdx.x, bn = blockIdx.y;
  const int lane = tid & 63, wv = tid >> 6;
  const int wm = wv >> 1, wn = wv & 1;
  const int m16 = lane & 15, q = lane >> 4;
  const int qs = q ^ ((m16 >> 1) & 3);          // read-side chunk swizzle (per-lane const)

  const int r0 = tid >> 2;
  const int qsw = (tid & 3) ^ ((r0 >> 1) & 3);
  const ushort* aG = A  + (size_t)(bm * 128 + r0) * 1024 + qsw * 8;
  const ushort* bG = Bm + (size_t)(bn * 128 + r0) * 1024 + qsw * 8;

  f32x4 acc[4][4] = {};

#define STAGE(buf, kk) do {                                   \
    load_lds16(aG + (kk), As[buf] + wv * 512);                \
    load_lds16(aG + 65536 + (kk), As[buf] + 2048 + wv * 512); \
    load_lds16(bG + (kk), Bs[buf] + wv * 512);                \
    load_lds16(bG + 65536 + (kk), Bs[buf] + 2048 + wv * 512); \
  } while (0)

#define COMPUTE(cur) do {                                                        \
    s8vec af[4], bfv[4];                                                         \
    _Pragma("unroll")                                                            \
    for (int i = 0; i < 4; ++i)                                                  \
      af[i] = *(const s8vec*)(As[cur] + (wm * 64 + i * 16 + m16) * 32 + qs * 8); \
    _Pragma("unroll")                                                            \
    for (int j = 0; j < 4; ++j)                                                  \
      bfv[j] = *(const s8vec*)(Bs[cur] + (wn * 64 + j * 16 + m16) * 32 + qs * 8);\
    _Pragma("unroll")                                                            \
    for (int i = 0; i < 4; ++i)                                                  \
      _Pragma("unroll")                                                          \
      for (int j = 0; j < 4; ++j)                                                \
        acc[i][j] = __builtin_amdgcn_mfma_f32_16x16x32_bf16(af[i], bfv[j],       \
                                                            acc[i][j], 0, 0, 0);\
  } while (0)

  STAGE(0, 0);                                  // prologue: tile 0 in flight
#pragma unroll 1
  for (int k0 = 0; k0 < 992; k0 += 32) {
    const int cur = (k0 >> 5) & 1;
    STAGE(cur ^ 1, k0 + 32);                    // issue next tile (8 loads now in flight)
    asm volatile("s_waitcnt vmcnt(4)\n\ts_barrier" ::: "memory");  // cur landed; next stays in flight
    COMPUTE(cur);
    asm volatile("s_barrier" ::: "memory");     // all waves done reading cur (no drain)
  }
  // epilogue: tile 31 (cur = 1), nothing left to prefetch
  asm volatile("s_waitcnt vmcnt(0)\n\ts_barrier" ::: "memory");
  COMPUTE(1);
#undef STAGE
#undef COMPUTE

  // C/D layout: col = lane&15, row = (lane>>4)*4 + r   [measured: learn_hip m89/m91]
  if (MODE == 0) {
    ushort* P = (ushort*)outp;
#pragma unroll
    for (int i = 0; i < 4; ++i)
#pragma unroll
      for (int r = 0; r < 4; ++r) {
        const int gr = bm * 128 + wm * 64 + i * 16 + q * 4 + r;
#pragma unroll
        for (int j = 0; j < 4; ++j) {
          const int gc = bn * 128 + wn * 64 + j * 16 + m16;
          const float z = acc[i][j][r] + bias[gc];
          const float p = 1.f / (1.f + expf(-z));
          if (gc < N_INT) P[(size_t)gr * 1024 + gc + 1] = f2b(p);  // +1 layer-aligned layout
        }
      }
  } else {
    float* O = (float*)outp;
#pragma unroll
    for (int i = 0; i < 4; ++i)
#pragma unroll
      for (int r = 0; r < 4; ++r) {
        const int gr = bm * 128 + wm * 64 + i * 16 + q * 4 + r;
#pragma unroll
        for (int j = 0; j < 4; ++j) {
          const int gc = bn * 128 + wn * 64 + j * 16 + m16;
          if (gc < N_OUT) O[(size_t)gr * 1000 + gc] = acc[i][j][r];
        }
      }
  }
}

// ---------------- tree: ROUTING ONLY (one row per wave, no LDS, no reductions) ----------------
__global__ __launch_bounds__(256) void tree_kernel(const ushort* __restrict__ probs,
                                                   ushort* __restrict__ path) {
  const int lane = threadIdx.x & 63;
  const int r = blockIdx.x * 4 + (threadIdx.x >> 6);   // 16384 waves, 1 row each
  const ushort* prow = probs + (size_t)r * 1024;

  const int hh  = (int)prow[lane];                    // cols 0..63 (layers 0..5)
  const ushort p6 = prow[64 + lane];
  const uint   p7 = *(const uint*)(prow + 128 + 2 * lane);
  const uint2  p8 = *(const uint2*)(prow + 256 + 4 * lane);
  const uint4  p9 = *(const uint4*)(prow + 512 + 8 * lane);

  // prefix chain down to the size-64 layer; lane = entry index there
  float v = 1.f;
#pragma unroll
  for (int t = 1; t <= 6; ++t) {
    const int ell = t - 1;
    const int e = lane >> (6 - t);
    const float p = b2f((ushort)__shfl(hh, (1 << ell) + (e >> 1)));   // idx <= 63
    v *= (e & 1) ? (1.f - p) : p;
  }

  float w[16];
  { const float p = b2f(p6); w[1] = v * (1.f - p); w[0] = v * p; }
  {
    const float pA = blo(p7), pB = bhi(p7);
    w[3] = w[1] * (1.f - pB); w[2] = w[1] * pB;
    w[1] = w[0] * (1.f - pA); w[0] = w[0] * pA;
  }
  {
    const float pv[4] = { blo(p8.x), bhi(p8.x), blo(p8.y), bhi(p8.y) };
#pragma unroll
    for (int i = 3; i >= 0; --i) {
      w[2 * i + 1] = w[i] * (1.f - pv[i]);
      w[2 * i]     = w[i] * pv[i];
    }
  }
  {
    const uint pv[4] = { p9.x, p9.y, p9.z, p9.w };
#pragma unroll
    for (int i = 7; i >= 0; --i) {
      const float p = (i & 1) ? bhi(pv[i >> 1]) : blo(pv[i >> 1]);
      w[2 * i + 1] = w[i] * (1.f - p);
      w[2 * i]     = w[i] * p;
    }
  }
  union { ushort u[16]; uint4 q4[2]; } pk;
#pragma unroll
  for (int i = 0; i < 16; ++i) pk.u[i] = f2b(w[i]);
  uint4* dst = (uint4*)(path + (size_t)r * 1024 + lane * 16);
  dst[0] = pk.q4[0];
  dst[1] = pk.q4[1];
}

// ---------------- accum: streaming S1/S2 from leaves (subtree-sum identity) ----------------
// pathnew_ell[j] (j < 2^ell, the only half the reference uses) == sum of leaves
// [j*K, (j+1)*K) because p + (1-p) = 1 at every split. Lanes 0..31 row A,
// lanes 32..63 row B. No serial chains.
__global__ __launch_bounds__(256) void accum_kernel(const ushort* __restrict__ probs,
                                                    const ushort* __restrict__ path,
                                                    float* __restrict__ Spart) {
  __shared__ float Ss[2048];    // [0..1023]=S1 by node id, [1024..2047]=S2
  for (int i = threadIdx.x; i < 2048; i += 256) Ss[i] = 0.f;
  __syncthreads();
  const int lane = threadIdx.x & 63;
  const int ll = lane & 31;
  const int half = lane >> 5;
  const int hb = half << 5;
  const int gw = blockIdx.x * 4 + (threadIdx.x >> 6);   // 4096 waves x 4 rows

  float a19[16] = {}, a29[16] = {};   // layer 9: j = 16*ll + i
  float a18[8]  = {}, a28[8]  = {};   // layer 8: j = 8*ll + i
  float a17[4]  = {}, a27[4]  = {};   // layer 7: j = 4*ll + i
  float a16[2]  = {}, a26[2]  = {};   // layer 6: j = 2*ll + i
  float t1[6] = {}, t2[6] = {};       // layers 0..5 (leader lanes per half)

#pragma unroll
  for (int it = 0; it < 2; ++it) {
    const int r = gw * 4 + it * 2 + half;   // half 0 -> row A, half 1 -> row B
    const ushort* prow = probs + (size_t)r * 1024;
    const ushort* wrow = path  + (size_t)r * 1024;

    const int   hlo = (int)prow[ll];           // cols 0..31 (layers 0..4 probs)
    const float p5  = b2f(prow[32 + ll]);      // layer-5 prob, node ll
    union { uint4 q[2]; ushort u[16]; } wl;    // leaves 16*ll .. 16*ll+15 (first 512 only)
    wl.q[0] = *(const uint4*)(wrow + 16 * ll);
    wl.q[1] = *(const uint4*)(wrow + 16 * ll + 8);
    union { uint4 q[2]; ushort u[16]; } j9;
    j9.q[0] = *(const uint4*)(prow + 512 + 16 * ll);
    j9.q[1] = *(const uint4*)(prow + 512 + 16 * ll + 8);
    union { uint4 q; ushort u[8]; } j8;
    j8.q = *(const uint4*)(prow + 256 + 8 * ll);
    union { uint2 q; ushort u[4]; } j7;
    j7.q = *(const uint2*)(prow + 128 + 4 * ll);
    union { uint q; ushort u[2]; } j6;
    j6.q = *(const uint*)(prow + 64 + 2 * ll);

    float w[16];
#pragma unroll
    for (int i = 0; i < 16; ++i) w[i] = b2f(wl.u[i]);
    float L8[8], L7[4], L6[2];
#pragma unroll
    for (int i = 0; i < 8; ++i) L8[i] = w[2 * i] + w[2 * i + 1];
#pragma unroll
    for (int i = 0; i < 4; ++i) L7[i] = L8[2 * i] + L8[2 * i + 1];
    L6[0] = L7[0] + L7[1]; L6[1] = L7[2] + L7[3];
    const float T = L6[0] + L6[1];             // = E64[ll] (16-leaf subtree sum)

#pragma unroll
    for (int i = 0; i < 16; ++i) { a19[i] += w[i];  a29[i] += b2f(j9.u[i]) * w[i]; }
#pragma unroll
    for (int i = 0; i < 8; ++i)  { a18[i] += L8[i]; a28[i] += b2f(j8.u[i]) * L8[i]; }
#pragma unroll
    for (int i = 0; i < 4; ++i)  { a17[i] += L7[i]; a27[i] += b2f(j7.u[i]) * L7[i]; }
#pragma unroll
    for (int i = 0; i < 2; ++i)  { a16[i] += L6[i]; a26[i] += b2f(j6.u[i]) * L6[i]; }

    // layers 0..5 via within-half shfl_xor subtree sums (all shfls hoisted, unguarded)
    t1[5] += T; t2[5] += p5 * T;
    const float T1 = T  + __shfl_xor(T, 1);    // E32[ll>>1]
    const float T2 = T1 + __shfl_xor(T1, 2);   // E16[ll>>2]
    const float T3 = T2 + __shfl_xor(T2, 4);   // E8 [ll>>3]
    const float T4 = T3 + __shfl_xor(T3, 8);   // E4 [ll>>4]
    const float T5 = T4 + __shfl_xor(T4, 16);  // E2 [0] (uniform in half)
    const float v4 = __shfl(T1, hb | ((2 * ll) & 31));
    const float v3 = __shfl(T2, hb | ((4 * ll) & 31));
    const float v2 = __shfl(T3, hb | ((8 * ll) & 31));
    const float v1 = __shfl(T4, hb | ((16 * ll) & 31));
    const float q4 = b2f((ushort)__shfl(hlo, hb | ((16 + ll) & 31)));
    const float q3 = b2f((ushort)__shfl(hlo, hb | ((8 + ll) & 31)));
    const float q2 = b2f((ushort)__shfl(hlo, hb | ((4 + ll) & 31)));
    const float q1 = b2f((ushort)__shfl(hlo, hb | ((2 + ll) & 31)));
    const float q0 = b2f((ushort)__shfl(hlo, hb | 1));
    if (ll < 16) { t1[4] += v4; t2[4] += q4 * v4; }
    if (ll < 8)  { t1[3] += v3; t2[3] += q3 * v3; }
    if (ll < 4)  { t1[2] += v2; t2[2] += q2 * v2; }
    if (ll < 2)  { t1[1] += v1; t2[1] += q1 * v1; }
    if (ll < 1)  { t1[0] += T5; t2[0] += q0 * T5; }
  }

  // cross-half combine (row A + row B partials -> lanes<32)
#pragma unroll
  for (int i = 0; i < 16; ++i) { a19[i] += __shfl_xor(a19[i], 32); a29[i] += __shfl_xor(a29[i], 32); }
#pragma unroll
  for (int i = 0; i < 8; ++i)  { a18[i] += __shfl_xor(a18[i], 32); a28[i] += __shfl_xor(a28[i], 32); }
#pragma unroll
  for (int i = 0; i < 4; ++i)  { a17[i] += __shfl_xor(a17[i], 32); a27[i] += __shfl_xor(a27[i], 32); }
#pragma unroll
  for (int i = 0; i < 2; ++i)  { a16[i] += __shfl_xor(a16[i], 32); a26[i] += __shfl_xor(a26[i], 32); }
#pragma unroll
  for (int i = 0; i < 6; ++i)  { t1[i] += __shfl_xor(t1[i], 32);   t2[i] += __shfl_xor(t2[i], 32); }

  if (lane < 32) {   // node id = (1<<ell)-1 + j; S2 mirrored at +1024
#pragma unroll
    for (int i = 0; i < 16; ++i) { atomicAdd(&Ss[511 + 16 * ll + i], a19[i]); atomicAdd(&Ss[1535 + 16 * ll + i], a29[i]); }
#pragma unroll
    for (int i = 0; i < 8; ++i)  { atomicAdd(&Ss[255 + 8 * ll + i],  a18[i]); atomicAdd(&Ss[1279 + 8 * ll + i],  a28[i]); }
#pragma unroll
    for (int i = 0; i < 4; ++i)  { atomicAdd(&Ss[127 + 4 * ll + i],  a17[i]); atomicAdd(&Ss[1151 + 4 * ll + i],  a27[i]); }
#pragma unroll
    for (int i = 0; i < 2; ++i)  { atomicAdd(&Ss[63 + 2 * ll + i],   a16[i]); atomicAdd(&Ss[1087 + 2 * ll + i],  a26[i]); }
    atomicAdd(&Ss[31 + ll], t1[5]); atomicAdd(&Ss[1055 + ll], t2[5]);
    if (ll < 16) { atomicAdd(&Ss[15 + ll], t1[4]); atomicAdd(&Ss[1039 + ll], t2[4]); }
    if (ll < 8)  { atomicAdd(&Ss[7 + ll],  t1[3]); atomicAdd(&Ss[1031 + ll], t2[3]); }
    if (ll < 4)  { atomicAdd(&Ss[3 + ll],  t1[2]); atomicAdd(&Ss[1027 + ll], t2[2]); }
    if (ll < 2)  { atomicAdd(&Ss[1 + ll],  t1[1]); atomicAdd(&Ss[1025 + ll], t2[1]); }
    if (ll < 1)  { atomicAdd(&Ss[0],       t1[0]); atomicAdd(&Ss[1024],      t2[0]); }
  }
  __syncthreads();
  // coalesced 8KB partial store into DEAD Xb region -- no aliasing with live data
  float* Sp = Spart + (size_t)blockIdx.x * 2048;
  for (int i = threadIdx.x; i < 2048; i += 256) Sp[i] = Ss[i];
}

// ---------------- reduce partials -> Sg (32 atomics/address, coalesced reads) ----------------
__global__ __launch_bounds__(256) void reduce_kernel(const float* __restrict__ Spart,
                                                     float* __restrict__ Sg) {
  const int t = threadIdx.x;
  float acc[8] = {};
  const float* base = Spart + (size_t)blockIdx.x * 32 * 2048;
  for (int b = 0; b < 32; ++b) {
    const float* p = base + (size_t)b * 2048;
#pragma unroll
    for (int k = 0; k < 8; ++k) acc[k] += p[t + 256 * k];
  }
#pragma unroll
  for (int k = 0; k < 8; ++k) {
    const int i = t + 256 * k;
    const int node = i & 1023;
    if (node < 1023) atomicAdd(&Sg[(i < 1024 ? 0 : 2048) + node], acc[k]);
  }
}

// ---------------- finalize: alphas + log-regularizer ----------------
__global__ __launch_bounds__(1024) void finalize_kernel(const float* __restrict__ Sg,
                                                        float* __restrict__ outreg) {
  const int tid = threadIdx.x;
  double val = 0.0;
  if (tid < 1023) {
    const int ell = 31 - __clz(tid + 1);           // node tid is in layer ell
    const double s1 = (double)Sg[tid];
    const double s2 = (double)Sg[2048 + tid];
    const double den = s1 + 1e-8;
    const double a0 = s2 / den;                    // alpha for even child
    const double a1 = (s1 - s2) / den;             // alpha for odd child
    const double f = 1e-3 * (1.0 / (double)(1 << ell));
    val = -0.5 * f * (log(a0) + log(1.0 - a0) + log(a1) + log(1.0 - a1));
  }
#pragma unroll
  for (int o = 32; o > 0; o >>= 1) val += __shfl_down(val, o, 64);
  __shared__ double partd[16];
  if ((tid & 63) == 0) partd[tid >> 6] = val;
  __syncthreads();
  if (tid == 0) {
    double t = 0.0;
    for (int i = 0; i < 16; ++i) t += partd[i];
    outreg[0] = (float)t;
  }
}

extern "C" void kernel_launch(void* const* d_in, const int* in_sizes, int n_in,
                              void* d_out, int out_size, void* d_ws, size_t ws_size,
                              hipStream_t stream) {
  const float* X     = (const float*)d_in[0];   // [16384,1024]
  const float* Wint  = (const float*)d_in[1];   // [1023,1025]
  const float* Wleaf = (const float*)d_in[2];   // [1000,1024]
  float* out = (float*)d_out;                   // [16384*1000] preds + [1] reg
  char* ws = (char*)d_ws;                       // needs ~105 MB

  ushort* Xb   = (ushort*)(ws + OFF_XB);
  ushort* W1   = (ushort*)(ws + OFF_W1);
  float*  bias = (float*)(ws + OFF_BIAS);
  ushort* prob = (ushort*)(ws + OFF_PROB);
  ushort* path = (ushort*)(ws + OFF_PATH);
  ushort* W2   = (ushort*)(ws + OFF_W2);
  float*  Sg   = (float*)(ws + OFF_SG);
  float*  Spart = (float*)(ws + OFF_XB);        // Xb is dead after gemm<0>

  (void)hipMemsetAsync(ws + OFF_SG, 0, 16384, stream);  // zero Sg
  cvt_all<<<24576, 256, 0, stream>>>((const float4*)X, (ushort4*)Xb,
                                     Wint, Wleaf, W1, W2, bias);
  gemm_bt<0><<<dim3(128, 8), 256, 0, stream>>>(Xb, W1, bias, (void*)prob);
  tree_kernel<<<4096, 256, 0, stream>>>(prob, path);
  gemm_bt<1><<<dim3(128, 8), 256, 0, stream>>>(path, W2, nullptr, (void*)out);
  accum_kernel<<<1024, 256, 0, stream>>>(prob, path, Spart);
  reduce_kernel<<<32, 256, 0, stream>>>(Spart, Sg);
  finalize_kernel<<<1, 1024, 0, stream>>>(Sg, out + (size_t)B_ROWS * N_OUT);
}

// Round 5
// 298.742 us; speedup vs baseline: 1.0319x; 1.0319x over previous
//
#include <hip/hip_runtime.h>
#include <hip/hip_bf16.h>

// Problem constants
#define B_ROWS 16384
#define K_DIM  1024
#define N_INT  1023
#define N_OUT  1000

using s8vec = __attribute__((ext_vector_type(8))) short;   // 8 bf16 (4 VGPRs) MFMA operand
using f32x4 = __attribute__((ext_vector_type(4))) float;   // MFMA accumulator

// Workspace layout (bytes). Total ~105 MB.
static const size_t OFF_XB   = 0;                        // bf16 [16384*1024]; DEAD after gemm<0> -> reused as Spart
static const size_t OFF_W1   = OFF_XB   + 33554432;      // bf16 [1024*1024] (row 1023 = 0)
static const size_t OFF_BIAS = OFF_W1   + 2097152;       // f32  [1024]
static const size_t OFF_PROB = OFF_BIAS + 4096;          // bf16 [16384*1024]; node j at col j+1
static const size_t OFF_PATH = OFF_PROB + 33554432;      // bf16 [16384*1024]
static const size_t OFF_W2   = OFF_PATH + 33554432;      // bf16 [1024*1024] (rows >=1000 = 0)
static const size_t OFF_SG   = OFF_W2   + 2097152;       // f32  [4096]: S1 at [node], S2 at [2048+node]

__device__ __forceinline__ float b2f(ushort u) {
  return __uint_as_float(((unsigned)u) << 16);
}
__device__ __forceinline__ float blo(unsigned u) { return __uint_as_float(u << 16); }
__device__ __forceinline__ float bhi(unsigned u) { return __uint_as_float(u & 0xffff0000u); }
__device__ __forceinline__ ushort f2b(float f) {
  unsigned u = __float_as_uint(f);
  u = u + 0x7FFFu + ((u >> 16) & 1u);   // RNE
  return (ushort)(u >> 16);
}

// async global->LDS, 16B per lane; LDS dest is wave-uniform base + lane*16
__device__ __forceinline__ void load_lds16(const ushort* g, ushort* l) {
  __builtin_amdgcn_global_load_lds((const __attribute__((address_space(1))) void*)g,
                                   (__attribute__((address_space(3))) void*)l,
                                   16, 0, 0);
}

// ---------------- fused converts (one launch) ----------------
__global__ __launch_bounds__(256) void cvt_all(const float4* __restrict__ X,
                                               ushort4* __restrict__ O,
                                               const float* __restrict__ Wi,
                                               const float* __restrict__ Wl,
                                               ushort* __restrict__ W1,
                                               ushort* __restrict__ W2,
                                               float* __restrict__ bias) {
  const int b = blockIdx.x;
  if (b < 16384) {
    const int i = b * 256 + threadIdx.x;
    const float4 v = X[i];
    ushort4 o;
    o.x = f2b(v.x); o.y = f2b(v.y); o.z = f2b(v.z); o.w = f2b(v.w);
    O[i] = o;
  } else {
    const int idx = (b - 16384) * 256 + threadIdx.x;   // [0, 2*2^20)
    if (idx < (1 << 20)) {
      const int n = idx >> 10, k = idx & 1023;
      const float v = (n < N_INT) ? Wi[n * 1025 + 1 + k] : 0.f;
      W1[idx] = f2b(v);
      if (k == 0) bias[n] = (n < N_INT) ? Wi[n * 1025] : 0.f;
    } else {
      const int j = idx - (1 << 20);
      const int n = j >> 10, k = j & 1023;
      const float v = (n < N_OUT) ? Wl[n * 1024 + k] : 0.f;
      W2[j] = f2b(v);
    }
  }
}

// ---------------- GEMM: C = A[M,K] * Bm[N,K]^T, 256x256 tile, 8 waves ----------------
// 256^2 deep-phase port (learn_hip m198/m201 regime): BM=BN=256, BK=64, 512 thr,
// 1 block/CU (128KB LDS), acc 128 VGPR/lane. Per K-tile: 2 phases of
// {12 ds_read_b128 -> 32 MFMA}; stages of K-tile t+2 issued mid-compute of t;
// COUNTED vmcnt(8) keeps next tile's 8 global_load_lds in flight across barriers.
// Publish barrier preceded by sched_barrier(0)+lgkmcnt(0): straggler ds_reads must
// complete before other waves' stage DMA can overwrite the buffer (rule #18 family).
// 8-slot XOR swizzle (slot = c ^ (row&7)) applied as inverse-perm on the GLOBAL
// source (gload_lds dest must stay linear) + XOR on ds_read addr -> 2-way max
// (free). Same both-sides scheme as the verified-0-conflict round-4 kernel.
// Grid (bm=64 fast, bn=4): linear id % 8 = bm%8 -> all 4 bn-blocks of an A strip
// share one XCD's L2.
template <int MODE>
__global__ __launch_bounds__(512, 2) void gemm_bt(const ushort* __restrict__ A,
                                                  const ushort* __restrict__ Bm,
                                                  const float* __restrict__ bias,
                                                  void* __restrict__ outp) {
  __shared__ ushort Al[2][16384];   // [buf][256 rows][64 cols] bf16, slot-swizzled
  __shared__ ushort Bl[2][16384];
  const int tid = threadIdx.x;
  const int bm = blockIdx.x, bn = blockIdx.y;
  const int lane = tid & 63, wv = tid >> 6;     // 8 waves
  const int wm = wv >> 2, wn = wv & 3;          // 2 (M) x 4 (N) wave grid
  const int m16 = lane & 15, q = lane >> 4;
  const int rs = m16 & 7;                       // read-side row-XOR key

  // staging: thread t writes 16B at row (t>>3), physical slot (t&7); source chunk
  // pre-swizzled so physical slot p of row r holds logical chunk p ^ (r&7).
  const int qsw = (tid & 7) ^ ((tid >> 3) & 7);
  const ushort* aGp = A  + (size_t)(bm * 256 + (tid >> 3)) * 1024 + qsw * 8;
  const ushort* bGp = Bm + (size_t)(bn * 256 + (tid >> 3)) * 1024 + qsw * 8;

  f32x4 acc[8][4] = {};
  s8vec af[8], bf[4];

  // stage one full K-tile (A 32KB + B 32KB) = 8 gload_lds/thread; kc = kt*64 ushorts
#define STAGE_KT(b, kc) do {                                      \
    load_lds16(aGp + (kc),          &Al[b][wv * 512]);            \
    load_lds16(aGp + 65536 + (kc),  &Al[b][4096  + wv * 512]);    \
    load_lds16(aGp + 131072 + (kc), &Al[b][8192  + wv * 512]);    \
    load_lds16(aGp + 196608 + (kc), &Al[b][12288 + wv * 512]);    \
    load_lds16(bGp + (kc),          &Bl[b][wv * 512]);            \
    load_lds16(bGp + 65536 + (kc),  &Bl[b][4096  + wv * 512]);    \
    load_lds16(bGp + 131072 + (kc), &Bl[b][8192  + wv * 512]);    \
    load_lds16(bGp + 196608 + (kc), &Bl[b][12288 + wv * 512]);    \
  } while (0)

  // read fragments for one k-half: c = kk>>3 (0 or 4); 12 x ds_read_b128
#define READF(b, c) do {                                                              \
    _Pragma("unroll")                                                                 \
    for (int mi = 0; mi < 8; ++mi)                                                    \
      af[mi] = *(const s8vec*)(&Al[b][(wm * 128 + mi * 16 + m16) * 64 +               \
                                      (((c) + q) ^ rs) * 8]);                         \
    _Pragma("unroll")                                                                 \
    for (int ni = 0; ni < 4; ++ni)                                                    \
      bf[ni] = *(const s8vec*)(&Bl[b][(wn * 64 + ni * 16 + m16) * 64 +                \
                                      (((c) + q) ^ rs) * 8]);                         \
  } while (0)

#define MF() do {                                                                     \
    __builtin_amdgcn_s_setprio(1);                                                    \
    _Pragma("unroll")                                                                 \
    for (int mi = 0; mi < 8; ++mi)                                                    \
      _Pragma("unroll")                                                               \
      for (int ni = 0; ni < 4; ++ni)                                                  \
        acc[mi][ni] = __builtin_amdgcn_mfma_f32_16x16x32_bf16(af[mi], bf[ni],         \
                                                              acc[mi][ni], 0, 0, 0);  \
    __builtin_amdgcn_s_setprio(0);                                                    \
  } while (0)

  STAGE_KT(0, 0);     // kt=0
  STAGE_KT(1, 64);    // kt=1   (16 loads outstanding)

#pragma unroll 1
  for (int it = 0; it < 7; ++it) {
    const int kc0 = it * 128;
    // ---- K-tile 2it (buf0) ----
    asm volatile("s_waitcnt vmcnt(8)\n\ts_barrier" ::: "memory");  // buf0 landed; buf1 in flight
    READF(0, 0); MF();
    READF(0, 4);
    __builtin_amdgcn_sched_barrier(0);                  // pin all buf0 reads above the drain
    asm volatile("s_waitcnt lgkmcnt(0)" ::: "memory");  // my reads complete before publishing
    asm volatile("s_barrier" ::: "memory");             // all waves done reading buf0
    STAGE_KT(0, kc0 + 128);                             // kt0+2 -> buf0 (DMA flies under MFMA)
    MF();
    // ---- K-tile 2it+1 (buf1) ----
    asm volatile("s_waitcnt vmcnt(8)\n\ts_barrier" ::: "memory");  // buf1 landed; new buf0 in flight
    READF(1, 0); MF();
    READF(1, 4);
    __builtin_amdgcn_sched_barrier(0);
    asm volatile("s_waitcnt lgkmcnt(0)" ::: "memory");
    asm volatile("s_barrier" ::: "memory");
    STAGE_KT(1, kc0 + 192);                             // kt1+2 -> buf1
    MF();
  }
  // peeled final iteration: kt=14 (buf0), kt=15 (buf1); nothing left to stage
  asm volatile("s_waitcnt vmcnt(8)\n\ts_barrier" ::: "memory");
  READF(0, 0); MF();
  READF(0, 4); MF();
  asm volatile("s_waitcnt vmcnt(0)\n\ts_barrier" ::: "memory");
  READF(1, 0); MF();
  READF(1, 4); MF();
#undef STAGE_KT
#undef READF
#undef MF

  // C/D layout: col = lane&15, row = (lane>>4)*4 + r   [measured: learn_hip m89/m91]
  if (MODE == 0) {
    ushort* P = (ushort*)outp;
#pragma unroll
    for (int mi = 0; mi < 8; ++mi)
#pragma unroll
      for (int r = 0; r < 4; ++r) {
        const int gr = bm * 256 + wm * 128 + mi * 16 + q * 4 + r;
#pragma unroll
        for (int ni = 0; ni < 4; ++ni) {
          const int gc = bn * 256 + wn * 64 + ni * 16 + m16;
          const float z = acc[mi][ni][r] + bias[gc];
          const float p = 1.f / (1.f + expf(-z));
          if (gc < N_INT) P[(size_t)gr * 1024 + gc + 1] = f2b(p);  // +1 layer-aligned layout
        }
      }
  } else {
    float* O = (float*)outp;
#pragma unroll
    for (int mi = 0; mi < 8; ++mi)
#pragma unroll
      for (int r = 0; r < 4; ++r) {
        const int gr = bm * 256 + wm * 128 + mi * 16 + q * 4 + r;
#pragma unroll
        for (int ni = 0; ni < 4; ++ni) {
          const int gc = bn * 256 + wn * 64 + ni * 16 + m16;
          if (gc < N_OUT) O[(size_t)gr * 1000 + gc] = acc[mi][ni][r];
        }
      }
  }
}

// ---------------- tree: ROUTING ONLY (one row per wave, no LDS, no reductions) ----------------
__global__ __launch_bounds__(256) void tree_kernel(const ushort* __restrict__ probs,
                                                   ushort* __restrict__ path) {
  const int lane = threadIdx.x & 63;
  const int r = blockIdx.x * 4 + (threadIdx.x >> 6);   // 16384 waves, 1 row each
  const ushort* prow = probs + (size_t)r * 1024;

  const int hh  = (int)prow[lane];                    // cols 0..63 (layers 0..5)
  const ushort p6 = prow[64 + lane];
  const uint   p7 = *(const uint*)(prow + 128 + 2 * lane);
  const uint2  p8 = *(const uint2*)(prow + 256 + 4 * lane);
  const uint4  p9 = *(const uint4*)(prow + 512 + 8 * lane);

  // prefix chain down to the size-64 layer; lane = entry index there
  float v = 1.f;
#pragma unroll
  for (int t = 1; t <= 6; ++t) {
    const int ell = t - 1;
    const int e = lane >> (6 - t);
    const float p = b2f((ushort)__shfl(hh, (1 << ell) + (e >> 1)));   // idx <= 63
    v *= (e & 1) ? (1.f - p) : p;
  }

  float w[16];
  { const float p = b2f(p6); w[1] = v * (1.f - p); w[0] = v * p; }
  {
    const float pA = blo(p7), pB = bhi(p7);
    w[3] = w[1] * (1.f - pB); w[2] = w[1] * pB;
    w[1] = w[0] * (1.f - pA); w[0] = w[0] * pA;
  }
  {
    const float pv[4] = { blo(p8.x), bhi(p8.x), blo(p8.y), bhi(p8.y) };
#pragma unroll
    for (int i = 3; i >= 0; --i) {
      w[2 * i + 1] = w[i] * (1.f - pv[i]);
      w[2 * i]     = w[i] * pv[i];
    }
  }
  {
    const uint pv[4] = { p9.x, p9.y, p9.z, p9.w };
#pragma unroll
    for (int i = 7; i >= 0; --i) {
      const float p = (i & 1) ? bhi(pv[i >> 1]) : blo(pv[i >> 1]);
      w[2 * i + 1] = w[i] * (1.f - p);
      w[2 * i]     = w[i] * p;
    }
  }
  union { ushort u[16]; uint4 q4[2]; } pk;
#pragma unroll
  for (int i = 0; i < 16; ++i) pk.u[i] = f2b(w[i]);
  uint4* dst = (uint4*)(path + (size_t)r * 1024 + lane * 16);
  dst[0] = pk.q4[0];
  dst[1] = pk.q4[1];
}

// ---------------- accum: streaming S1/S2 from leaves (subtree-sum identity) ----------------
// pathnew_ell[j] (j < 2^ell, the only half the reference uses) == sum of leaves
// [j*K, (j+1)*K) because p + (1-p) = 1 at every split. Lanes 0..31 row A,
// lanes 32..63 row B. No serial chains.
__global__ __launch_bounds__(256) void accum_kernel(const ushort* __restrict__ probs,
                                                    const ushort* __restrict__ path,
                                                    float* __restrict__ Spart) {
  __shared__ float Ss[2048];    // [0..1023]=S1 by node id, [1024..2047]=S2
  for (int i = threadIdx.x; i < 2048; i += 256) Ss[i] = 0.f;
  __syncthreads();
  const int lane = threadIdx.x & 63;
  const int ll = lane & 31;
  const int half = lane >> 5;
  const int hb = half << 5;
  const int gw = blockIdx.x * 4 + (threadIdx.x >> 6);   // 4096 waves x 4 rows

  float a19[16] = {}, a29[16] = {};   // layer 9: j = 16*ll + i
  float a18[8]  = {}, a28[8]  = {};   // layer 8: j = 8*ll + i
  float a17[4]  = {}, a27[4]  = {};   // layer 7: j = 4*ll + i
  float a16[2]  = {}, a26[2]  = {};   // layer 6: j = 2*ll + i
  float t1[6] = {}, t2[6] = {};       // layers 0..5 (leader lanes per half)

#pragma unroll
  for (int it = 0; it < 2; ++it) {
    const int r = gw * 4 + it * 2 + half;   // half 0 -> row A, half 1 -> row B
    const ushort* prow = probs + (size_t)r * 1024;
    const ushort* wrow = path  + (size_t)r * 1024;

    const int   hlo = (int)prow[ll];           // cols 0..31 (layers 0..4 probs)
    const float p5  = b2f(prow[32 + ll]);      // layer-5 prob, node ll
    union { uint4 q[2]; ushort u[16]; } wl;    // leaves 16*ll .. 16*ll+15 (first 512 only)
    wl.q[0] = *(const uint4*)(wrow + 16 * ll);
    wl.q[1] = *(const uint4*)(wrow + 16 * ll + 8);
    union { uint4 q[2]; ushort u[16]; } j9;
    j9.q[0] = *(const uint4*)(prow + 512 + 16 * ll);
    j9.q[1] = *(const uint4*)(prow + 512 + 16 * ll + 8);
    union { uint4 q; ushort u[8]; } j8;
    j8.q = *(const uint4*)(prow + 256 + 8 * ll);
    union { uint2 q; ushort u[4]; } j7;
    j7.q = *(const uint2*)(prow + 128 + 4 * ll);
    union { uint q; ushort u[2]; } j6;
    j6.q = *(const uint*)(prow + 64 + 2 * ll);

    float w[16];
#pragma unroll
    for (int i = 0; i < 16; ++i) w[i] = b2f(wl.u[i]);
    float L8[8], L7[4], L6[2];
#pragma unroll
    for (int i = 0; i < 8; ++i) L8[i] = w[2 * i] + w[2 * i + 1];
#pragma unroll
    for (int i = 0; i < 4; ++i) L7[i] = L8[2 * i] + L8[2 * i + 1];
    L6[0] = L7[0] + L7[1]; L6[1] = L7[2] + L7[3];
    const float T = L6[0] + L6[1];             // = E64[ll] (16-leaf subtree sum)

#pragma unroll
    for (int i = 0; i < 16; ++i) { a19[i] += w[i];  a29[i] += b2f(j9.u[i]) * w[i]; }
#pragma unroll
    for (int i = 0; i < 8; ++i)  { a18[i] += L8[i]; a28[i] += b2f(j8.u[i]) * L8[i]; }
#pragma unroll
    for (int i = 0; i < 4; ++i)  { a17[i] += L7[i]; a27[i] += b2f(j7.u[i]) * L7[i]; }
#pragma unroll
    for (int i = 0; i < 2; ++i)  { a16[i] += L6[i]; a26[i] += b2f(j6.u[i]) * L6[i]; }

    // layers 0..5 via within-half shfl_xor subtree sums (all shfls hoisted, unguarded)
    t1[5] += T; t2[5] += p5 * T;
    const float T1 = T  + __shfl_xor(T, 1);    // E32[ll>>1]
    const float T2 = T1 + __shfl_xor(T1, 2);   // E16[ll>>2]
    const float T3 = T2 + __shfl_xor(T2, 4);   // E8 [ll>>3]
    const float T4 = T3 + __shfl_xor(T3, 8);   // E4 [ll>>4]
    const float T5 = T4 + __shfl_xor(T4, 16);  // E2 [0] (uniform in half)
    const float v4 = __shfl(T1, hb | ((2 * ll) & 31));
    const float v3 = __shfl(T2, hb | ((4 * ll) & 31));
    const float v2 = __shfl(T3, hb | ((8 * ll) & 31));
    const float v1 = __shfl(T4, hb | ((16 * ll) & 31));
    const float q4 = b2f((ushort)__shfl(hlo, hb | ((16 + ll) & 31)));
    const float q3 = b2f((ushort)__shfl(hlo, hb | ((8 + ll) & 31)));
    const float q2 = b2f((ushort)__shfl(hlo, hb | ((4 + ll) & 31)));
    const float q1 = b2f((ushort)__shfl(hlo, hb | ((2 + ll) & 31)));
    const float q0 = b2f((ushort)__shfl(hlo, hb | 1));
    if (ll < 16) { t1[4] += v4; t2[4] += q4 * v4; }
    if (ll < 8)  { t1[3] += v3; t2[3] += q3 * v3; }
    if (ll < 4)  { t1[2] += v2; t2[2] += q2 * v2; }
    if (ll < 2)  { t1[1] += v1; t2[1] += q1 * v1; }
    if (ll < 1)  { t1[0] += T5; t2[0] += q0 * T5; }
  }

  // cross-half combine (row A + row B partials -> lanes<32)
#pragma unroll
  for (int i = 0; i < 16; ++i) { a19[i] += __shfl_xor(a19[i], 32); a29[i] += __shfl_xor(a29[i], 32); }
#pragma unroll
  for (int i = 0; i < 8; ++i)  { a18[i] += __shfl_xor(a18[i], 32); a28[i] += __shfl_xor(a28[i], 32); }
#pragma unroll
  for (int i = 0; i < 4; ++i)  { a17[i] += __shfl_xor(a17[i], 32); a27[i] += __shfl_xor(a27[i], 32); }
#pragma unroll
  for (int i = 0; i < 2; ++i)  { a16[i] += __shfl_xor(a16[i], 32); a26[i] += __shfl_xor(a26[i], 32); }
#pragma unroll
  for (int i = 0; i < 6; ++i)  { t1[i] += __shfl_xor(t1[i], 32);   t2[i] += __shfl_xor(t2[i], 32); }

  if (lane < 32) {   // node id = (1<<ell)-1 + j; S2 mirrored at +1024
#pragma unroll
    for (int i = 0; i < 16; ++i) { atomicAdd(&Ss[511 + 16 * ll + i], a19[i]); atomicAdd(&Ss[1535 + 16 * ll + i], a29[i]); }
#pragma unroll
    for (int i = 0; i < 8; ++i)  { atomicAdd(&Ss[255 + 8 * ll + i],  a18[i]); atomicAdd(&Ss[1279 + 8 * ll + i],  a28[i]); }
#pragma unroll
    for (int i = 0; i < 4; ++i)  { atomicAdd(&Ss[127 + 4 * ll + i],  a17[i]); atomicAdd(&Ss[1151 + 4 * ll + i],  a27[i]); }
#pragma unroll
    for (int i = 0; i < 2; ++i)  { atomicAdd(&Ss[63 + 2 * ll + i],   a16[i]); atomicAdd(&Ss[1087 + 2 * ll + i],  a26[i]); }
    atomicAdd(&Ss[31 + ll], t1[5]); atomicAdd(&Ss[1055 + ll], t2[5]);
    if (ll < 16) { atomicAdd(&Ss[15 + ll], t1[4]); atomicAdd(&Ss[1039 + ll], t2[4]); }
    if (ll < 8)  { atomicAdd(&Ss[7 + ll],  t1[3]); atomicAdd(&Ss[1031 + ll], t2[3]); }
    if (ll < 4)  { atomicAdd(&Ss[3 + ll],  t1[2]); atomicAdd(&Ss[1027 + ll], t2[2]); }
    if (ll < 2)  { atomicAdd(&Ss[1 + ll],  t1[1]); atomicAdd(&Ss[1025 + ll], t2[1]); }
    if (ll < 1)  { atomicAdd(&Ss[0],       t1[0]); atomicAdd(&Ss[1024],      t2[0]); }
  }
  __syncthreads();
  // coalesced 8KB partial store into DEAD Xb region -- no aliasing with live data
  float* Sp = Spart + (size_t)blockIdx.x * 2048;
  for (int i = threadIdx.x; i < 2048; i += 256) Sp[i] = Ss[i];
}

// ---------------- reduce partials -> Sg (32 atomics/address, coalesced reads) ----------------
__global__ __launch_bounds__(256) void reduce_kernel(const float* __restrict__ Spart,
                                                     float* __restrict__ Sg) {
  const int t = threadIdx.x;
  float acc[8] = {};
  const float* base = Spart + (size_t)blockIdx.x * 32 * 2048;
  for (int b = 0; b < 32; ++b) {
    const float* p = base + (size_t)b * 2048;
#pragma unroll
    for (int k = 0; k < 8; ++k) acc[k] += p[t + 256 * k];
  }
#pragma unroll
  for (int k = 0; k < 8; ++k) {
    const int i = t + 256 * k;
    const int node = i & 1023;
    if (node < 1023) atomicAdd(&Sg[(i < 1024 ? 0 : 2048) + node], acc[k]);
  }
}

// ---------------- finalize: alphas + log-regularizer ----------------
__global__ __launch_bounds__(1024) void finalize_kernel(const float* __restrict__ Sg,
                                                        float* __restrict__ outreg) {
  const int tid = threadIdx.x;
  double val = 0.0;
  if (tid < 1023) {
    const int ell = 31 - __clz(tid + 1);           // node tid is in layer ell
    const double s1 = (double)Sg[tid];
    const double s2 = (double)Sg[2048 + tid];
    const double den = s1 + 1e-8;
    const double a0 = s2 / den;                    // alpha for even child
    const double a1 = (s1 - s2) / den;             // alpha for odd child
    const double f = 1e-3 * (1.0 / (double)(1 << ell));
    val = -0.5 * f * (log(a0) + log(1.0 - a0) + log(a1) + log(1.0 - a1));
  }
#pragma unroll
  for (int o = 32; o > 0; o >>= 1) val += __shfl_down(val, o, 64);
  __shared__ double partd[16];
  if ((tid & 63) == 0) partd[tid >> 6] = val;
  __syncthreads();
  if (tid == 0) {
    double t = 0.0;
    for (int i = 0; i < 16; ++i) t += partd[i];
    outreg[0] = (float)t;
  }
}

extern "C" void kernel_launch(void* const* d_in, const int* in_sizes, int n_in,
                              void* d_out, int out_size, void* d_ws, size_t ws_size,
                              hipStream_t stream) {
  const float* X     = (const float*)d_in[0];   // [16384,1024]
  const float* Wint  = (const float*)d_in[1];   // [1023,1025]
  const float* Wleaf = (const float*)d_in[2];   // [1000,1024]
  float* out = (float*)d_out;                   // [16384*1000] preds + [1] reg
  char* ws = (char*)d_ws;                       // needs ~105 MB

  ushort* Xb   = (ushort*)(ws + OFF_XB);
  ushort* W1   = (ushort*)(ws + OFF_W1);
  float*  bias = (float*)(ws + OFF_BIAS);
  ushort* prob = (ushort*)(ws + OFF_PROB);
  ushort* path = (ushort*)(ws + OFF_PATH);
  ushort* W2   = (ushort*)(ws + OFF_W2);
  float*  Sg   = (float*)(ws + OFF_SG);
  float*  Spart = (float*)(ws + OFF_XB);        // Xb is dead after gemm<0>

  (void)hipMemsetAsync(ws + OFF_SG, 0, 16384, stream);  // zero Sg
  cvt_all<<<24576, 256, 0, stream>>>((const float4*)X, (ushort4*)Xb,
                                     Wint, Wleaf, W1, W2, bias);
  gemm_bt<0><<<dim3(64, 4), 512, 0, stream>>>(Xb, W1, bias, (void*)prob);
  tree_kernel<<<4096, 256, 0, stream>>>(prob, path);
  gemm_bt<1><<<dim3(64, 4), 512, 0, stream>>>(path, W2, nullptr, (void*)out);
  accum_kernel<<<1024, 256, 0, stream>>>(prob, path, Spart);
  reduce_kernel<<<32, 256, 0, stream>>>(Spart, Sg);
  finalize_kernel<<<1, 1024, 0, stream>>>(Sg, out + (size_t)B_ROWS * N_OUT);
}

// Round 6
// 295.877 us; speedup vs baseline: 1.0419x; 1.0097x over previous
//
#include <hip/hip_runtime.h>
#include <hip/hip_bf16.h>

// Problem constants
#define B_ROWS 16384
#define K_DIM  1024
#define N_INT  1023
#define N_OUT  1000

using s8vec = __attribute__((ext_vector_type(8))) short;   // 8 bf16 (4 VGPRs) MFMA operand
using f32x4 = __attribute__((ext_vector_type(4))) float;   // MFMA accumulator

// Workspace layout (bytes). Total ~105 MB.
static const size_t OFF_XB   = 0;                        // bf16 [16384*1024]; DEAD after gemm<0> -> reused as Spart
static const size_t OFF_W1   = OFF_XB   + 33554432;      // bf16 [1024*1024] (row 1023 = 0)
static const size_t OFF_BIAS = OFF_W1   + 2097152;       // f32  [1024]
static const size_t OFF_PROB = OFF_BIAS + 4096;          // bf16 [16384*1024]; node j at col j+1
static const size_t OFF_PATH = OFF_PROB + 33554432;      // bf16 [16384*1024]
static const size_t OFF_W2   = OFF_PATH + 33554432;      // bf16 [1024*1024] (rows >=1000 = 0)
static const size_t OFF_SG   = OFF_W2   + 2097152;       // f32  [4096]: S1 at [node], S2 at [2048+node]

__device__ __forceinline__ float b2f(ushort u) {
  return __uint_as_float(((unsigned)u) << 16);
}
__device__ __forceinline__ float blo(unsigned u) { return __uint_as_float(u << 16); }
__device__ __forceinline__ float bhi(unsigned u) { return __uint_as_float(u & 0xffff0000u); }
__device__ __forceinline__ ushort f2b(float f) {
  unsigned u = __float_as_uint(f);
  u = u + 0x7FFFu + ((u >> 16) & 1u);   // RNE
  return (ushort)(u >> 16);
}

// async global->LDS, 16B per lane; LDS dest is wave-uniform base + lane*16
__device__ __forceinline__ void load_lds16(const ushort* g, ushort* l) {
  __builtin_amdgcn_global_load_lds((const __attribute__((address_space(1))) void*)g,
                                   (__attribute__((address_space(3))) void*)l,
                                   16, 0, 0);
}

// ---------------- fused converts (one launch) ----------------
__global__ __launch_bounds__(256) void cvt_all(const float4* __restrict__ X,
                                               ushort4* __restrict__ O,
                                               const float* __restrict__ Wi,
                                               const float* __restrict__ Wl,
                                               ushort* __restrict__ W1,
                                               ushort* __restrict__ W2,
                                               float* __restrict__ bias) {
  const int b = blockIdx.x;
  if (b < 16384) {
    const int i = b * 256 + threadIdx.x;
    const float4 v = X[i];
    ushort4 o;
    o.x = f2b(v.x); o.y = f2b(v.y); o.z = f2b(v.z); o.w = f2b(v.w);
    O[i] = o;
  } else {
    const int idx = (b - 16384) * 256 + threadIdx.x;   // [0, 2*2^20)
    if (idx < (1 << 20)) {
      const int n = idx >> 10, k = idx & 1023;
      const float v = (n < N_INT) ? Wi[n * 1025 + 1 + k] : 0.f;
      W1[idx] = f2b(v);
      if (k == 0) bias[n] = (n < N_INT) ? Wi[n * 1025] : 0.f;
    } else {
      const int j = idx - (1 << 20);
      const int n = j >> 10, k = j & 1023;
      const float v = (n < N_OUT) ? Wl[n * 1024 + k] : 0.f;
      W2[j] = f2b(v);
    }
  }
}

// ---------------- GEMM: C = A[M,K] * Bm[N,K]^T, 128x128 tile, 4 waves ----------------
// Round-4 proven structure (best measured: 62 us): T3+T4 2-phase pipeline, LDS
// double-buffer, STAGE(next) at TOP of iter, COUNTED s_waitcnt vmcnt(4) (current
// tile's 4 gload_lds land; next tile's 4 stay in flight across both barriers),
// raw s_barrier (no vmcnt(0) drain). Chunk swizzle on GLOBAL source + ds_read.
// Round-6 edits: (a) __launch_bounds__(256,5): 5 x 32KB = exactly 160KB LDS ->
// 5 blocks/CU of latency cover (was 4); (b) MODE-0 sigmoid via __expf + rcp
// (~6 VALU/elem vs ~30 for libm expf -- epilogue was the VALUBusy hotspot).
// Grid (bm fast, bn=8): all 8 bn-blocks of an A strip share one XCD's L2.
template <int MODE>
__global__ __launch_bounds__(256, 5) void gemm_bt(const ushort* __restrict__ A,
                                                  const ushort* __restrict__ Bm,
                                                  const float* __restrict__ bias,
                                                  void* __restrict__ outp) {
  __shared__ ushort As[2][4096];   // [buf][128 rows][32 k] bf16, chunk-swizzled
  __shared__ ushort Bs[2][4096];
  const int tid = threadIdx.x;
  const int bm = blockIdx.x, bn = blockIdx.y;
  const int lane = tid & 63, wv = tid >> 6;
  const int wm = wv >> 1, wn = wv & 1;
  const int m16 = lane & 15, q = lane >> 4;
  const int qs = q ^ ((m16 >> 1) & 3);          // read-side chunk swizzle (per-lane const)

  const int r0 = tid >> 2;
  const int qsw = (tid & 3) ^ ((r0 >> 1) & 3);
  const ushort* aG = A  + (size_t)(bm * 128 + r0) * 1024 + qsw * 8;
  const ushort* bG = Bm + (size_t)(bn * 128 + r0) * 1024 + qsw * 8;

  f32x4 acc[4][4] = {};

#define STAGE(buf, kk) do {                                   \
    load_lds16(aG + (kk), As[buf] + wv * 512);                \
    load_lds16(aG + 65536 + (kk), As[buf] + 2048 + wv * 512); \
    load_lds16(bG + (kk), Bs[buf] + wv * 512);                \
    load_lds16(bG + 65536 + (kk), Bs[buf] + 2048 + wv * 512); \
  } while (0)

#define COMPUTE(cur) do {                                                        \
    s8vec af[4], bfv[4];                                                         \
    _Pragma("unroll")                                                            \
    for (int i = 0; i < 4; ++i)                                                  \
      af[i] = *(const s8vec*)(As[cur] + (wm * 64 + i * 16 + m16) * 32 + qs * 8); \
    _Pragma("unroll")                                                            \
    for (int j = 0; j < 4; ++j)                                                  \
      bfv[j] = *(const s8vec*)(Bs[cur] + (wn * 64 + j * 16 + m16) * 32 + qs * 8);\
    _Pragma("unroll")                                                            \
    for (int i = 0; i < 4; ++i)                                                  \
      _Pragma("unroll")                                                          \
      for (int j = 0; j < 4; ++j)                                                \
        acc[i][j] = __builtin_amdgcn_mfma_f32_16x16x32_bf16(af[i], bfv[j],       \
                                                            acc[i][j], 0, 0, 0);\
  } while (0)

  STAGE(0, 0);                                  // prologue: tile 0 in flight
#pragma unroll 1
  for (int k0 = 0; k0 < 992; k0 += 32) {
    const int cur = (k0 >> 5) & 1;
    STAGE(cur ^ 1, k0 + 32);                    // issue next tile (8 loads now in flight)
    asm volatile("s_waitcnt vmcnt(4)\n\ts_barrier" ::: "memory");  // cur landed; next stays in flight
    COMPUTE(cur);
    asm volatile("s_barrier" ::: "memory");     // all waves done reading cur (no drain)
  }
  // epilogue: tile 31 (cur = 1), nothing left to prefetch
  asm volatile("s_waitcnt vmcnt(0)\n\ts_barrier" ::: "memory");
  COMPUTE(1);
#undef STAGE
#undef COMPUTE

  // C/D layout: col = lane&15, row = (lane>>4)*4 + r   [measured: learn_hip m89/m91]
  if (MODE == 0) {
    ushort* P = (ushort*)outp;
#pragma unroll
    for (int i = 0; i < 4; ++i)
#pragma unroll
      for (int r = 0; r < 4; ++r) {
        const int gr = bm * 128 + wm * 64 + i * 16 + q * 4 + r;
#pragma unroll
        for (int j = 0; j < 4; ++j) {
          const int gc = bn * 128 + wn * 64 + j * 16 + m16;
          const float z = acc[i][j][r] + bias[gc];
          // fast sigmoid: v_exp + v_rcp (output is bf16 -- 8-bit mantissa,
          // approx error invisible after rounding)
          const float p = __builtin_amdgcn_rcpf(1.f + __expf(-z));
          if (gc < N_INT) P[(size_t)gr * 1024 + gc + 1] = f2b(p);  // +1 layer-aligned layout
        }
      }
  } else {
    float* O = (float*)outp;
#pragma unroll
    for (int i = 0; i < 4; ++i)
#pragma unroll
      for (int r = 0; r < 4; ++r) {
        const int gr = bm * 128 + wm * 64 + i * 16 + q * 4 + r;
#pragma unroll
        for (int j = 0; j < 4; ++j) {
          const int gc = bn * 128 + wn * 64 + j * 16 + m16;
          if (gc < N_OUT) O[(size_t)gr * 1000 + gc] = acc[i][j][r];
        }
      }
  }
}

// ---------------- tree: routing + S1/S2 accumulation in ONE pass ----------------
// 1024 blocks x 4 waves x 4 rows. Routing: 12-shfl prefix chain + 4 in-register
// split levels -> 16 bf16 leaves stored. Accumulation uses the subtree-sum
// identity (p + (1-p) = 1): pathnew_ell[j] (j < 2^ell, the only half the
// reference uses) = sum of leaves [j*2^(9-ell), (j+1)*2^(9-ell)) -- all derived
// from the in-register w[16], so NO re-read of path/prob (kills the old
// accum_kernel launch + its ~48MB traffic). Lane L owns leaves 16L..16L+15.
__global__ __launch_bounds__(256) void tree_kernel(const ushort* __restrict__ probs,
                                                   ushort* __restrict__ path,
                                                   float* __restrict__ Spart) {
  __shared__ float Ss[2048];    // [0..1023]=S1 by node id, [1024..2047]=S2
  for (int i = threadIdx.x; i < 2048; i += 256) Ss[i] = 0.f;
  __syncthreads();
  const int lane = threadIdx.x & 63;
  const int gw = blockIdx.x * 4 + (threadIdx.x >> 6);   // 4096 waves x 4 rows

  float a19[16] = {}, a29[16] = {};   // layer 9: j = 16*lane + i (lane<32)
  float a18[8]  = {}, a28[8]  = {};   // layer 8: j = 8*lane + i
  float a17[4]  = {}, a27[4]  = {};   // layer 7: j = 4*lane + i
  float a16[2]  = {}, a26[2]  = {};   // layer 6: j = 2*lane + i
  float t1[6] = {}, t2[6] = {};       // layers 0..5

#pragma unroll 1
  for (int rr = 0; rr < 4; ++rr) {
    const int r = gw * 4 + rr;
    const ushort* prow = probs + (size_t)r * 1024;

    const int hh  = (int)prow[lane];                    // cols 0..63 (layers 0..5)
    const ushort p6 = prow[64 + lane];
    const uint   p7 = *(const uint*)(prow + 128 + 2 * lane);
    const uint2  p8 = *(const uint2*)(prow + 256 + 4 * lane);
    const uint4  p9 = *(const uint4*)(prow + 512 + 8 * lane);

    // ---- routing ----
    float v = 1.f;
#pragma unroll
    for (int t = 1; t <= 6; ++t) {
      const int ell = t - 1;
      const int e = lane >> (6 - t);
      const float p = b2f((ushort)__shfl(hh, (1 << ell) + (e >> 1)));   // idx <= 63
      v *= (e & 1) ? (1.f - p) : p;
    }
    float w[16];
    { const float p = b2f(p6); w[1] = v * (1.f - p); w[0] = v * p; }
    {
      const float pA = blo(p7), pB = bhi(p7);
      w[3] = w[1] * (1.f - pB); w[2] = w[1] * pB;
      w[1] = w[0] * (1.f - pA); w[0] = w[0] * pA;
    }
    {
      const float pv[4] = { blo(p8.x), bhi(p8.x), blo(p8.y), bhi(p8.y) };
#pragma unroll
      for (int i = 3; i >= 0; --i) {
        w[2 * i + 1] = w[i] * (1.f - pv[i]);
        w[2 * i]     = w[i] * pv[i];
      }
    }
    {
      const uint pv[4] = { p9.x, p9.y, p9.z, p9.w };
#pragma unroll
      for (int i = 7; i >= 0; --i) {
        const float p = (i & 1) ? bhi(pv[i >> 1]) : blo(pv[i >> 1]);
        w[2 * i + 1] = w[i] * (1.f - p);
        w[2 * i]     = w[i] * p;
      }
    }
    union { ushort u[16]; uint4 q4[2]; } pk;
#pragma unroll
    for (int i = 0; i < 16; ++i) pk.u[i] = f2b(w[i]);
    uint4* dst = (uint4*)(path + (size_t)r * 1024 + lane * 16);
    dst[0] = pk.q4[0];
    dst[1] = pk.q4[1];

    // ---- accumulation from in-register leaves ----
    float L8[8], L7[4], L6[2];
#pragma unroll
    for (int i = 0; i < 8; ++i) L8[i] = w[2 * i] + w[2 * i + 1];
#pragma unroll
    for (int i = 0; i < 4; ++i) L7[i] = L8[2 * i] + L8[2 * i + 1];
    L6[0] = L7[0] + L7[1]; L6[1] = L7[2] + L7[3];
    const float T = L6[0] + L6[1];             // 16-leaf subtree sum = pathnew_5[lane]

    // layer 9..6 node probs live in lanes 2*lane, 2*lane+1 (shfls unguarded)
    uint s9[8];
    s9[0] = (uint)__shfl((int)p9.x, (2 * lane) & 63);
    s9[1] = (uint)__shfl((int)p9.y, (2 * lane) & 63);
    s9[2] = (uint)__shfl((int)p9.z, (2 * lane) & 63);
    s9[3] = (uint)__shfl((int)p9.w, (2 * lane) & 63);
    s9[4] = (uint)__shfl((int)p9.x, (2 * lane + 1) & 63);
    s9[5] = (uint)__shfl((int)p9.y, (2 * lane + 1) & 63);
    s9[6] = (uint)__shfl((int)p9.z, (2 * lane + 1) & 63);
    s9[7] = (uint)__shfl((int)p9.w, (2 * lane + 1) & 63);
    const uint u80 = (uint)__shfl((int)p8.x, (2 * lane) & 63);
    const uint u81 = (uint)__shfl((int)p8.y, (2 * lane) & 63);
    const uint u82 = (uint)__shfl((int)p8.x, (2 * lane + 1) & 63);
    const uint u83 = (uint)__shfl((int)p8.y, (2 * lane + 1) & 63);
    const uint ua7 = (uint)__shfl((int)p7, (2 * lane) & 63);
    const uint ub7 = (uint)__shfl((int)p7, (2 * lane + 1) & 63);
    const int  j60 = __shfl((int)p6, (2 * lane) & 63);
    const int  j61 = __shfl((int)p6, (2 * lane + 1) & 63);
    if (lane < 32) {
#pragma unroll
      for (int i = 0; i < 16; ++i) {
        const uint u = s9[i >> 1];
        const float pj = (i & 1) ? bhi(u) : blo(u);
        a19[i] += w[i]; a29[i] += pj * w[i];
      }
      a18[0] += L8[0]; a28[0] += blo(u80) * L8[0];
      a18[1] += L8[1]; a28[1] += bhi(u80) * L8[1];
      a18[2] += L8[2]; a28[2] += blo(u81) * L8[2];
      a18[3] += L8[3]; a28[3] += bhi(u81) * L8[3];
      a18[4] += L8[4]; a28[4] += blo(u82) * L8[4];
      a18[5] += L8[5]; a28[5] += bhi(u82) * L8[5];
      a18[6] += L8[6]; a28[6] += blo(u83) * L8[6];
      a18[7] += L8[7]; a28[7] += bhi(u83) * L8[7];
      a17[0] += L7[0]; a27[0] += blo(ua7) * L7[0];
      a17[1] += L7[1]; a27[1] += bhi(ua7) * L7[1];
      a17[2] += L7[2]; a27[2] += blo(ub7) * L7[2];
      a17[3] += L7[3]; a27[3] += bhi(ub7) * L7[3];
      a16[0] += L6[0]; a26[0] += b2f((ushort)j60) * L6[0];
      a16[1] += L6[1]; a26[1] += b2f((ushort)j61) * L6[1];
    }

    // layers 5..0 via shfl_xor subtree-sum tree (all shfls unguarded)
    const float T1 = T  + __shfl_xor(T, 1);    // pathnew_4 at even lanes
    const float T2 = T1 + __shfl_xor(T1, 2);   // pathnew_3 at lanes 4j
    const float T3 = T2 + __shfl_xor(T2, 4);   // pathnew_2 at lanes 8j
    const float T4 = T3 + __shfl_xor(T3, 8);   // pathnew_1 at lanes 16j
    const float T5 = T4 + __shfl_xor(T4, 16);  // pathnew_0[0] at lane 0
    const float v4 = __shfl(T1, (2 * lane) & 63);
    const float v3 = __shfl(T2, (4 * lane) & 63);
    const float v2 = __shfl(T3, (8 * lane) & 63);
    const float v1 = __shfl(T4, (16 * lane) & 63);
    const float v0 = __shfl(T5, 0);
    const float q5 = b2f((ushort)__shfl(hh, (32 + lane) & 63));
    const float q4 = b2f((ushort)__shfl(hh, (16 + lane) & 63));
    const float q3 = b2f((ushort)__shfl(hh, (8 + lane) & 63));
    const float q2 = b2f((ushort)__shfl(hh, (4 + lane) & 63));
    const float q1 = b2f((ushort)__shfl(hh, (2 + lane) & 63));
    const float q0 = b2f((ushort)__shfl(hh, 1));
    if (lane < 32) { t1[5] += T;  t2[5] += q5 * T; }
    if (lane < 16) { t1[4] += v4; t2[4] += q4 * v4; }
    if (lane < 8)  { t1[3] += v3; t2[3] += q3 * v3; }
    if (lane < 4)  { t1[2] += v2; t2[2] += q2 * v2; }
    if (lane < 2)  { t1[1] += v1; t2[1] += q1 * v1; }
    if (lane < 1)  { t1[0] += v0; t2[0] += q0 * v0; }
  }

  // merge register accumulators -> LDS (node id = 2^ell - 1 + j; S2 at +1024)
  if (lane < 32) {
#pragma unroll
    for (int i = 0; i < 16; ++i) { atomicAdd(&Ss[511 + 16 * lane + i], a19[i]); atomicAdd(&Ss[1535 + 16 * lane + i], a29[i]); }
#pragma unroll
    for (int i = 0; i < 8; ++i)  { atomicAdd(&Ss[255 + 8 * lane + i],  a18[i]); atomicAdd(&Ss[1279 + 8 * lane + i],  a28[i]); }
#pragma unroll
    for (int i = 0; i < 4; ++i)  { atomicAdd(&Ss[127 + 4 * lane + i],  a17[i]); atomicAdd(&Ss[1151 + 4 * lane + i],  a27[i]); }
#pragma unroll
    for (int i = 0; i < 2; ++i)  { atomicAdd(&Ss[63 + 2 * lane + i],   a16[i]); atomicAdd(&Ss[1087 + 2 * lane + i],  a26[i]); }
    atomicAdd(&Ss[31 + lane], t1[5]); atomicAdd(&Ss[1055 + lane], t2[5]);
    if (lane < 16) { atomicAdd(&Ss[15 + lane], t1[4]); atomicAdd(&Ss[1039 + lane], t2[4]); }
    if (lane < 8)  { atomicAdd(&Ss[7 + lane],  t1[3]); atomicAdd(&Ss[1031 + lane], t2[3]); }
    if (lane < 4)  { atomicAdd(&Ss[3 + lane],  t1[2]); atomicAdd(&Ss[1027 + lane], t2[2]); }
    if (lane < 2)  { atomicAdd(&Ss[1 + lane],  t1[1]); atomicAdd(&Ss[1025 + lane], t2[1]); }
    if (lane < 1)  { atomicAdd(&Ss[0],         t1[0]); atomicAdd(&Ss[1024],        t2[0]); }
  }
  __syncthreads();
  // coalesced 8KB partial store into DEAD Xb region -- no aliasing with live data
  float* Sp = Spart + (size_t)blockIdx.x * 2048;
  for (int i = threadIdx.x; i < 2048; i += 256) Sp[i] = Ss[i];
}

// ---------------- reduce partials -> Sg (32 atomics/address, coalesced reads) ----------------
__global__ __launch_bounds__(256) void reduce_kernel(const float* __restrict__ Spart,
                                                     float* __restrict__ Sg) {
  const int t = threadIdx.x;
  float acc[8] = {};
  const float* base = Spart + (size_t)blockIdx.x * 32 * 2048;
  for (int b = 0; b < 32; ++b) {
    const float* p = base + (size_t)b * 2048;
#pragma unroll
    for (int k = 0; k < 8; ++k) acc[k] += p[t + 256 * k];
  }
#pragma unroll
  for (int k = 0; k < 8; ++k) {
    const int i = t + 256 * k;
    const int node = i & 1023;
    if (node < 1023) atomicAdd(&Sg[(i < 1024 ? 0 : 2048) + node], acc[k]);
  }
}

// ---------------- finalize: alphas + log-regularizer ----------------
__global__ __launch_bounds__(1024) void finalize_kernel(const float* __restrict__ Sg,
                                                        float* __restrict__ outreg) {
  const int tid = threadIdx.x;
  double val = 0.0;
  if (tid < 1023) {
    const int ell = 31 - __clz(tid + 1);           // node tid is in layer ell
    const double s1 = (double)Sg[tid];
    const double s2 = (double)Sg[2048 + tid];
    const double den = s1 + 1e-8;
    const double a0 = s2 / den;                    // alpha for even child
    const double a1 = (s1 - s2) / den;             // alpha for odd child
    const double f = 1e-3 * (1.0 / (double)(1 << ell));
    val = -0.5 * f * (log(a0) + log(1.0 - a0) + log(a1) + log(1.0 - a1));
  }
#pragma unroll
  for (int o = 32; o > 0; o >>= 1) val += __shfl_down(val, o, 64);
  __shared__ double partd[16];
  if ((tid & 63) == 0) partd[tid >> 6] = val;
  __syncthreads();
  if (tid == 0) {
    double t = 0.0;
    for (int i = 0; i < 16; ++i) t += partd[i];
    outreg[0] = (float)t;
  }
}

extern "C" void kernel_launch(void* const* d_in, const int* in_sizes, int n_in,
                              void* d_out, int out_size, void* d_ws, size_t ws_size,
                              hipStream_t stream) {
  const float* X     = (const float*)d_in[0];   // [16384,1024]
  const float* Wint  = (const float*)d_in[1];   // [1023,1025]
  const float* Wleaf = (const float*)d_in[2];   // [1000,1024]
  float* out = (float*)d_out;                   // [16384*1000] preds + [1] reg
  char* ws = (char*)d_ws;                       // needs ~105 MB

  ushort* Xb   = (ushort*)(ws + OFF_XB);
  ushort* W1   = (ushort*)(ws + OFF_W1);
  float*  bias = (float*)(ws + OFF_BIAS);
  ushort* prob = (ushort*)(ws + OFF_PROB);
  ushort* path = (ushort*)(ws + OFF_PATH);
  ushort* W2   = (ushort*)(ws + OFF_W2);
  float*  Sg   = (float*)(ws + OFF_SG);
  float*  Spart = (float*)(ws + OFF_XB);        // Xb is dead after gemm<0>

  (void)hipMemsetAsync(ws + OFF_SG, 0, 16384, stream);  // zero Sg
  cvt_all<<<24576, 256, 0, stream>>>((const float4*)X, (ushort4*)Xb,
                                     Wint, Wleaf, W1, W2, bias);
  gemm_bt<0><<<dim3(128, 8), 256, 0, stream>>>(Xb, W1, bias, (void*)prob);
  tree_kernel<<<1024, 256, 0, stream>>>(prob, path, Spart);
  gemm_bt<1><<<dim3(128, 8), 256, 0, stream>>>(path, W2, nullptr, (void*)out);
  reduce_kernel<<<32, 256, 0, stream>>>(Spart, Sg);
  finalize_kernel<<<1, 1024, 0, stream>>>(Sg, out + (size_t)B_ROWS * N_OUT);
}